// Round 5
// baseline (34.500 us; speedup 1.0000x reference)
//
#include <hip/hip_runtime.h>
#include <hip/hip_bf16.h>

typedef __attribute__((ext_vector_type(8))) short short8;   // 8 bf16 (4 VGPRs)
typedef __attribute__((ext_vector_type(4))) float f32x4;    // MFMA acc

#define NPTS 131072

__device__ inline unsigned short f2bf(float f) {
    unsigned u = __float_as_uint(f);
    u = (u + 0x7FFFu + ((u >> 16) & 1u)) >> 16;   // RNE
    return (unsigned short)u;
}

__device__ inline unsigned pack2(float a, float b) {
    union { __hip_bfloat162 h; unsigned u; } v;
    v.h = __float22bfloat162_rn(float2{a, b});    // v_cvt_pk_bf16_f32 (RNE)
    return v.u;
}

// ---------------- prep: fold weights into bf16 MFMA-ready tables ------------
// w1t[e][k]     : k 0..15 = (Ws@W1) qcf channels, 16..18 = win rows, 19..31 = 0
// w2t[e][pi(d)] : = W2[d][e], pi(d) = (d&15)*8 + (d>>4)   (K-axis permuted)
// beff[e]       : b1[e] + bs @ W1[0:128]
// w3t[q][k]     : block-diag W3 in sigma-permuted K, sigma(e) = (e&15)*2 + (e>>4)
__global__ __launch_bounds__(256) void prep_kernel(
    const float* __restrict__ Ws, const float* __restrict__ bs,
    const float* __restrict__ W1, const float* __restrict__ b1,
    const float* __restrict__ W2, const float* __restrict__ W3,
    unsigned short* __restrict__ w1t, unsigned short* __restrict__ w2t,
    float* __restrict__ beff, unsigned short* __restrict__ w3t)
{
    int t = blockIdx.x * 256 + threadIdx.x;
    if (t < 4096) {
        int e = t >> 5, k = t & 31;
        float v = 0.f;
        if (k < 16) {
            for (int d = 0; d < 128; ++d) v = fmaf(Ws[k*128 + d], W1[d*128 + e], v);
        } else if (k < 19) {
            v = W1[(128 + (k - 16))*128 + e];
        }
        w1t[e*32 + k] = f2bf(v);
    } else if (t < 8192) {
        int t2 = t - 4096;
        int e = t2 >> 7, d = t2 & 127;
        w2t[e*128 + ((d & 15)*8 + (d >> 4))] = f2bf(W2[d*32 + e]);
    } else if (t < 8320) {
        int e = t - 8192;
        float v = b1[e];
        for (int d = 0; d < 128; ++d) v = fmaf(bs[d], W1[d*128 + e], v);
        beff[e] = v;
    } else if (t < 8832) {
        int i = t - 8320;
        int q = i >> 5, k = i & 31;
        int e = (k & 1)*16 + (k >> 1);        // sigma^-1(k)
        int r = e >> 3, f = e & 7;
        float v = 0.f;
        if (q < 12) {
            int r2 = q / 3, o = q - r2*3;
            if (r == r2) v = W3[f*3 + o];
        }
        w3t[q*32 + k] = f2bf(v);
    }
}

// ---------------- main fused kernel: one 16-point tile per wave -------------
// Per-wave-private LDS; __syncthreads() between every write->read phase.
//   Xb  @0    : 16 x 40 bf16 (80 B stride)   = 1280 B
//   H1b @1280 : 16 x 136 bf16 (272 B stride) = 4352 B  (pi-permuted cols)
//   H2p @5632 : 16 x 40 bf16 (80 B stride)   = 1280 B  (sigma-permuted cols)
//   Wb  @6912 : 16x8 f32 = 512 B ; Ib @7424 : 16x8 int = 512 B
#define WREG 7936

__global__ __launch_bounds__(256, 4) void decoder_kernel(
    const float* __restrict__ qcf, const int* __restrict__ didx,
    const float* __restrict__ dwin, const float* __restrict__ bones,
    const unsigned short* __restrict__ w1t, const unsigned short* __restrict__ w2t,
    const float* __restrict__ beff, const float* __restrict__ b2,
    const unsigned short* __restrict__ w3t, const float* __restrict__ b3,
    float* __restrict__ out)
{
    __shared__ unsigned char lds[4 * WREG];

    const int tid  = threadIdx.x;
    const int wave = tid >> 6;
    const int lane = tid & 63;
    unsigned char* wbase = lds + wave * WREG;
    unsigned short* Xb  = (unsigned short*)(wbase);
    unsigned short* H1b = (unsigned short*)(wbase + 1280);
    unsigned short* H2p = (unsigned short*)(wbase + 5632);
    float*          Wb  = (float*)(wbase + 6912);
    int*            Ib  = (int*)(wbase + 7424);

    const int q4  = lane >> 4;
    const int l16 = lane & 15;

    const int gw   = blockIdx.x * 4 + wave;
    const int base = gw * 16;          // one 16-point tile per wave

    // ---- P0: IDW weights: 2 passes x (8 pts x 8 k) -------------------------
#pragma unroll
    for (int ph = 0; ph < 2; ++ph) {
        const int pl = ph*8 + (lane >> 3);
        const int k  = lane & 7;
        const int p  = base + pl;
        const int id = didx[p*8 + k];
        const float bx = bones[id*3+0], by = bones[id*3+1], bz = bones[id*3+2];
        const float rx = dwin[p*3+0] - bx;
        const float ry = dwin[p*3+1] - by;
        const float rz = dwin[p*3+2] - bz;
        const float dist = sqrtf(fmaf(rx,rx, fmaf(ry,ry, fmaf(rz,rz, 1e-8f))));
        const float w = 1.0f / (dist + 1e-8f);
        float s = w;
        s += __shfl_xor(s, 1);
        s += __shfl_xor(s, 2);
        s += __shfl_xor(s, 4);
        Wb[pl*8 + k] = w / s;
        Ib[pl*8 + k] = id;
    }
    __syncthreads();

    // ---- P1: interp in qcf(16) space, build X bf16 -------------------------
#pragma unroll
    for (int ps = 0; ps < 4; ++ps) {
        const int pl = ps*4 + q4;
        const int4   i0 = *(const int4*)(Ib + pl*8);
        const int4   i1 = *(const int4*)(Ib + pl*8 + 4);
        const float4 w0 = *(const float4*)(Wb + pl*8);
        const float4 w1 = *(const float4*)(Wb + pl*8 + 4);
        float acc = 0.f;
        acc = fmaf(w0.x, qcf[i0.x*16 + l16], acc);
        acc = fmaf(w0.y, qcf[i0.y*16 + l16], acc);
        acc = fmaf(w0.z, qcf[i0.z*16 + l16], acc);
        acc = fmaf(w0.w, qcf[i0.w*16 + l16], acc);
        acc = fmaf(w1.x, qcf[i1.x*16 + l16], acc);
        acc = fmaf(w1.y, qcf[i1.y*16 + l16], acc);
        acc = fmaf(w1.z, qcf[i1.z*16 + l16], acc);
        acc = fmaf(w1.w, qcf[i1.w*16 + l16], acc);
        Xb[pl*40 + l16] = f2bf(acc);
        float wv = 0.f;
        if (l16 < 3) wv = dwin[(base + pl)*3 + l16];
        Xb[pl*40 + 16 + l16] = f2bf(wv);        // k=16..18 win, 19..31 zero
    }
    __syncthreads();

    // ---- P2: layer 1: [16x32] @ [32x128] via 8 MFMA, weights from global ---
    const short8 a1 = *(const short8*)(Xb + l16*40 + q4*8);
    f32x4 acc1[8];
#pragma unroll
    for (int dt = 0; dt < 8; ++dt) {
        const short8 w1f = *(const short8*)(w1t + (dt*16 + l16)*32 + q4*8);
        const float  bv  = beff[dt*16 + l16];
        f32x4 c = { bv, bv, bv, bv };
        acc1[dt] = __builtin_amdgcn_mfma_f32_16x16x32_bf16(a1, w1f, c, 0, 0, 0);
    }
    // relu + pack to pi-permuted H1: lane owns cols l16*8+dt -> 4x b128 write
#pragma unroll
    for (int r = 0; r < 4; ++r) {
        union { unsigned u[4]; short8 s; } pk;
        pk.u[0] = pack2(fmaxf(acc1[0][r],0.f), fmaxf(acc1[1][r],0.f));
        pk.u[1] = pack2(fmaxf(acc1[2][r],0.f), fmaxf(acc1[3][r],0.f));
        pk.u[2] = pack2(fmaxf(acc1[4][r],0.f), fmaxf(acc1[5][r],0.f));
        pk.u[3] = pack2(fmaxf(acc1[6][r],0.f), fmaxf(acc1[7][r],0.f));
        *(short8*)(H1b + (q4*4 + r)*136 + l16*8) = pk.s;
    }
    __syncthreads();

    // ---- P3: layer 2: [16x128] @ [128x32] via 8 MFMA (pi-space K) ----------
    f32x4 acc2[2];
#pragma unroll
    for (int et = 0; et < 2; ++et) {
        const float bv = b2[et*16 + l16];
        acc2[et] = f32x4{ bv, bv, bv, bv };
    }
#pragma unroll
    for (int kt = 0; kt < 4; ++kt) {
        const short8 a2   = *(const short8*)(H1b + l16*136 + kt*32 + q4*8);
        const short8 w2f0 = *(const short8*)(w2t + (l16)*128      + kt*32 + q4*8);
        const short8 w2f1 = *(const short8*)(w2t + (16 + l16)*128 + kt*32 + q4*8);
        acc2[0] = __builtin_amdgcn_mfma_f32_16x16x32_bf16(a2, w2f0, acc2[0], 0, 0, 0);
        acc2[1] = __builtin_amdgcn_mfma_f32_16x16x32_bf16(a2, w2f1, acc2[1], 0, 0, 0);
    }
    // relu + pack to sigma-permuted H2: lane owns cols l16*2+et -> 4x b32 write
#pragma unroll
    for (int r = 0; r < 4; ++r) {
        unsigned p01 = pack2(fmaxf(acc2[0][r],0.f), fmaxf(acc2[1][r],0.f));
        *(unsigned*)(H2p + (q4*4 + r)*40 + l16*2) = p01;
    }
    __syncthreads();

    // ---- P4: layer 3: [16x32] @ [32x12] via 1 MFMA + residual --------------
    const short8 a3  = *(const short8*)(H2p + l16*40 + q4*8);
    const short8 w3f = *(const short8*)(w3t + l16*32 + q4*8);
    const int o = l16 - (l16/3)*3;
    const float b3o = (l16 < 12) ? b3[o] : 0.f;
    f32x4 c3 = { b3o, b3o, b3o, b3o };
    f32x4 o3 = __builtin_amdgcn_mfma_f32_16x16x32_bf16(a3, w3f, c3, 0, 0, 0);
    if (l16 < 12) {
#pragma unroll
        for (int r = 0; r < 4; ++r) {
            const int pt = base + q4*4 + r;
            out[(size_t)pt*12 + l16] = dwin[pt*3 + o] + o3[r];
        }
    }
}

extern "C" void kernel_launch(void* const* d_in, const int* in_sizes, int n_in,
                              void* d_out, int out_size, void* d_ws, size_t ws_size,
                              hipStream_t stream) {
    const float* qcf   = (const float*)d_in[0];
    const int*   didx  = (const int*)  d_in[1];
    const float* dwin  = (const float*)d_in[2];
    const float* bones = (const float*)d_in[3];
    // d_in[4] = K (always 8)
    const float* Ws = (const float*)d_in[5];
    const float* bs = (const float*)d_in[6];
    const float* W1 = (const float*)d_in[7];
    const float* b1 = (const float*)d_in[8];
    const float* W2 = (const float*)d_in[9];
    const float* b2 = (const float*)d_in[10];
    const float* W3 = (const float*)d_in[11];
    const float* b3 = (const float*)d_in[12];
    float* out = (float*)d_out;

    unsigned short* w1t  = (unsigned short*)d_ws;                    // 8 KB
    unsigned short* w2t  = (unsigned short*)((char*)d_ws + 8192);    // 8 KB
    float*          beff = (float*)((char*)d_ws + 16384);            // 512 B
    unsigned short* w3t  = (unsigned short*)((char*)d_ws + 16896);   // 1 KB

    hipLaunchKernelGGL(prep_kernel, dim3(35), dim3(256), 0, stream,
                       Ws, bs, W1, b1, W2, W3, w1t, w2t, beff, w3t);
    hipLaunchKernelGGL(decoder_kernel, dim3(2048), dim3(256), 0, stream,
                       qcf, didx, dwin, bones, w1t, w2t, beff, b2, w3t, b3, out);
}